// Round 1
// 67.678 us; speedup vs baseline: 1.0366x; 1.0366x over previous
//
#include <hip/hip_runtime.h>
#include <math.h>

#define HW 256
#define MINNORM 1.17549435e-38f   // 2^-126, f32 min normal

// R13: LAYOUT CHANGE. Old: 1 batch/wave (lane=j), 1024 waves, 1/SIMD -> the
// per-step chain (mul -> 4 DPP -> 3 readlane -> adds -> max -> rcp -> mul)
// ran with zero TLP and unfillable readlane/trans hazards; R12 proved that
// layout scheduling-saturated.
// New: 4 batches/wave (row r = lane>>4), 16 lanes/batch, 3 support slots/lane
// (j = slot*16 + lane16; j in [42,47] are identically 0: cd0 FTZ-flushes at
// j>=42 and the recurrence is multiplicative, so they never repopulate).
//  - per-step issue amortized 4x across batches
//  - row sum = 4 DPP adds (quad xor1, quad xor2, row_ror:8, row_ror:4): by
//    add-commutativity the total is BIT-UNIFORM across the 16 lanes -> no
//    readlane, no broadcast, no cross-row combine on the chain.
// NUMERICS (R10 discipline): state path keeps flush+normalize op-for-op per
// step: pg = (j-csf)*inv (clip dropped ONLY where it fires on exact-zero cd
// lanes, contributing +/-0 to sums); mult = fma(pg,sgn,base) == s1?pg:1-pg
// bit-exactly; prod = cd*mult (HW FTZ); norm = fmax(sum,1e-6); invn = rcpf;
// cd = prod*invn (HW FTZ). Only the sum ASSOCIATION changes (ulp class, same
// liberty as the passing rcp-vs-divide / DPP-vs-XLA order deviations).
// R11 kept: p_z is a direct nonneg sum (cd*pg), never S - p2.

template <int CTRL>
__device__ __forceinline__ float dpp_add(float x) {
    // x + dpp_perm(x); quad_perm/ror have no OOB lanes
    int s = __builtin_amdgcn_update_dpp(0, __builtin_bit_cast(int, x),
                                        CTRL, 0xf, 0xf, true);
    return x + __builtin_bit_cast(float, s);
}

// Bit-uniform row-of-16 dual total, stages interleaved (independent chains
// hide each other's VALU->DPP wait states).
// quad xor1 (0xB1), quad xor2 (0x4E): commutative-pair adds -> quad-uniform.
// row_ror:8 (0x128): quads get {A+C,B+D,C+A,D+B} -> two values, quad-uniform.
// row_ror:4 (0x124): every lane adds the other value -> (A+C)+(B+D) up to
// outer-add commutativity -> identical bits in all 16 lanes.
__device__ __forceinline__ void row_total2(float x, float y,
                                           float& sx, float& sy) {
    x = dpp_add<0xB1>(x);   y = dpp_add<0xB1>(y);
    x = dpp_add<0x4E>(x);   y = dpp_add<0x4E>(y);
    x = dpp_add<0x128>(x);  y = dpp_add<0x128>(y);
    x = dpp_add<0x124>(x);  y = dpp_add<0x124>(y);
    sx = x; sy = y;
}

__global__ void __launch_bounds__(64, 1)
spair_count_kl(const float* __restrict__ z_pres,
               const float* __restrict__ z_prob,
               float* __restrict__ out) {
    // f32 denorm mode = flush in+out (FP_DENORM[1:0]=0), matching XLA FTZ.
    // (bits [5:4] of MODE -> f32 only; the double-precision init is unaffected)
    float tok;
    asm volatile("s_setreg_imm32_b32 hwreg(HW_REG_MODE, 4, 2), 0\n\t"
                 "v_mov_b32 %0, 0" : "=v"(tok));

    __shared__ float invt[HW];

    const int lane = threadIdx.x;        // 0..63
    const int l16  = lane & 15;          // lane within row
    const int row  = lane >> 4;          // 0..3
    const int b    = blockIdx.x * 4 + row;

    // 1/den table, bit-identical to 1.0f/(float)(HW-i) (correctly-rounded div)
#pragma unroll
    for (int i = 0; i < 4; ++i)
        invt[i * 64 + lane] = 1.0f / (float)(HW - (i * 64 + lane));
    __syncthreads();

    // ---- cd0 init (R4..R9 semantics, verbatim math): j = slot*16+l16 ----
    const float e2f = (float)exp(2.0);                    // f32(exp(2))
    const float pf  = (float)(1.0 / ((double)e2f + 1.0)); // p in f32
    const double pd = (double)pf;
    const double l2p = log2(pd);
    float cd0, cd1, cd2;
    {
        float c[3];
#pragma unroll
        for (int sl = 0; sl < 3; ++sl) {
            const int j = sl * 16 + l16;
            const double powj = exp2((double)j * l2p);     // accurate p^j
            float v = (float)((1.0 - pd) * powj);          // (1-p)*p^j, f32
            c[sl] = (v < MINNORM) ? 0.0f : v;              // j>=42 flushes
        }
        float ssum = (c[0] + c[1]) + c[2];
        ssum = dpp_add<0xB1>(ssum);  ssum = dpp_add<0x4E>(ssum);
        ssum = dpp_add<0x128>(ssum); ssum = dpp_add<0x124>(ssum);
        cd0 = c[0] / ssum; cd1 = c[1] / ssum; cd2 = c[2] / ssum;
    }
    cd0 += tok; cd1 += tok; cd2 += tok;   // order recurrence after setreg
    float csf = tok;
    const float jf0 = (float)l16;
    const float jf1 = (float)(16 + l16);
    const float jf2 = (float)(32 + l16);

    const float* presb = z_pres + (size_t)b * HW;
    const float* probb = z_prob + (size_t)b * HW;
    float* outb = out + (size_t)b * HW;

    bool dead = false;

#pragma unroll 1
    for (int k = 0; k < 16; ++k) {
        float mypz = 0.0f;        // this lane captures step i = k*16 + l16
        float p2last = 0.0f;
        if (!dead) {
#pragma unroll
            for (int c4 = 0; c4 < 4; ++c4) {
                // row-uniform 16B chunks: 4 samples + 4 precomputed 1/den
                const float4 zp4 = *reinterpret_cast<const float4*>(presb + k * 16 + c4 * 4);
                const float4 iv4 = *reinterpret_cast<const float4*>(&invt[k * 16 + c4 * 4]);
#pragma unroll
                for (int u = 0; u < 4; ++u) {
                    const int ii = c4 * 4 + u;   // step within chunk, 0..15
                    const float zp  = (u == 0) ? zp4.x : (u == 1) ? zp4.y
                                    : (u == 2) ? zp4.z : zp4.w;
                    const float inv = (u == 0) ? iv4.x : (u == 1) ? iv4.y
                                    : (u == 2) ? iv4.z : iv4.w;

                    // sample = round-half-even in {0,1}
                    const float s    = rintf(zp);
                    const float sgn  = fmaf(s, 2.0f, -1.0f);   // +1 / -1, exact
                    const float base = 1.0f - s;               //  0 / +1, exact

                    // pg = (j - csf)*inv: exact int subtract, one rounding —
                    // identical to R12's t*inv on every lane with cd!=0.
                    // (lanes with j<csf or j>=42 have cd==0 exactly; their
                    //  out-of-clip pg contributes only +/-0 to every sum)
                    const float t0 = jf0 - csf, t1 = jf1 - csf, t2 = jf2 - csf;
                    const float pg0 = t0 * inv, pg1 = t1 * inv, pg2 = t2 * inv;

                    // mult = s1 ? pg : 1-pg, as single-rounded fma (bit-equal)
                    const float m0 = fmaf(pg0, sgn, base);
                    const float m1 = fmaf(pg1, sgn, base);
                    const float m2 = fmaf(pg2, sgn, base);

                    // ---- STATE + OUTPUT products (HW-FTZ) ----
                    const float pr0 = cd0 * m0, pr1 = cd1 * m1, pr2 = cd2 * m2;
                    const float y0 = cd0 * pg0, y1 = cd1 * pg1, y2 = cd2 * pg2;

                    float p2, p1s;
                    row_total2((pr0 + pr1) + pr2, (y0 + y1) + y2, p2, p1s);

                    const float norm = fmaxf(p2, 1e-6f);       // clip(sum,1e-6,inf)
                    const float invn = __builtin_amdgcn_rcpf(norm);
                    cd0 = pr0 * invn; cd1 = pr1 * invn; cd2 = pr2 * invn;
                    csf += s;

                    // s1: ref p_z terms == norm terms exactly -> p2.
                    const float pz = (s != 0.0f) ? p2 : p1s;
                    mypz = (l16 == ii) ? pz : mypz;
                    p2last = p2;   // only last assignment survives (dead rows stay 0)
                }
            }
            // wave exits only when ALL 4 rows are dead; dead rows meanwhile
            // produce pz = +/-0 through the normal path (== ref closed form).
            if (__ballot(p2last != 0.0f) == 0ULL) dead = true;
        }

        // KL for this lane's step (i = k*16 + l16); mypz==0 on dead steps is
        // exactly the ref's p_z=0 closed form.
        const float prob = probb[k * 16 + l16];
        const float pz = mypz;
        const float kl = prob * (logf(prob + 1e-9f) - logf(pz + 1e-9f))
                       + (1.0f - prob) * (logf((1.0f - prob) + 1e-9f)
                                        - logf((1.0f - pz) + 1e-9f));
        outb[k * 16 + l16] = kl;   // 64B per row, 4 rows per wave
    }
}

extern "C" void kernel_launch(void* const* d_in, const int* in_sizes, int n_in,
                              void* d_out, int out_size, void* d_ws, size_t ws_size,
                              hipStream_t stream) {
    const float* z_pres = (const float*)d_in[0];      // setup_inputs order
    const float* z_prob = (const float*)d_in[1];
    float* out = (float*)d_out;
    const int nbatch = in_sizes[0] / HW;              // 1024
    spair_count_kl<<<dim3(nbatch / 4), dim3(64), 0, stream>>>(z_pres, z_prob, out);
}